// Round 1
// baseline (1143.819 us; speedup 1.0000x reference)
//
#include <hip/hip_runtime.h>

#define H 128
#define MB 64          // rows (edges or nodes) per block
#define LDA 264        // LDS row stride for [64 x 256] tile (+8 pad)
#define LDB 136        // LDS row stride for [64 x 128] tiles (+8 pad)

typedef __attribute__((ext_vector_type(8))) short bf16x8;
typedef __attribute__((ext_vector_type(4))) short s16x4;
typedef __attribute__((ext_vector_type(2))) short s16x2;
typedef __attribute__((ext_vector_type(4))) float f32x4;

__device__ __forceinline__ short f2bf(float f) {
    union { float f; unsigned u; } v; v.f = f;
    unsigned r = v.u + 0x7FFF + ((v.u >> 16) & 1);   // RTNE
    return (short)(r >> 16);
}
__device__ __forceinline__ float bf2f(short s) {
    union { unsigned u; float f; } v;
    v.u = ((unsigned)(unsigned short)s) << 16;
    return v.f;
}

// ---------------- weight prep: fp32 [K,N] -> bf16 transposed [N,K] ----------------
__global__ __launch_bounds__(256) void prep_weights(
    const float* __restrict__ W1, const float* __restrict__ W2,
    const float* __restrict__ WL,
    short* __restrict__ W1T, short* __restrict__ W2T, short* __restrict__ WLT)
{
    int tid = blockIdx.x * 256 + threadIdx.x;      // 0..32767
    {   // W1: [256,128] -> W1T [128][256]
        int n = tid >> 8, k = tid & 255;
        W1T[n * 256 + k] = f2bf(W1[k * 128 + n]);
    }
    if (tid < 16384) {  // W2, W_lift: [128,128] -> [128][128]
        int n = tid >> 7, k = tid & 127;
        W2T[n * 128 + k] = f2bf(W2[k * 128 + n]);
        WLT[n * 128 + k] = f2bf(WL[k * 128 + n]);
    }
}

// ---------------- CSR build ----------------
// eidx is the flat [2][E] int array: i<E -> src of edge i, i>=E -> dst of edge i-E.
__global__ __launch_bounds__(256) void hist_kernel(
    const int* __restrict__ eidx, int* __restrict__ deg, int M /*2E*/)
{
    int i = blockIdx.x * 256 + threadIdx.x;
    if (i < M) atomicAdd(&deg[eidx[i]], 1);
}

// single-block exclusive scan: deg[0..N) -> off[0..N]; deg becomes the fill cursor.
__global__ __launch_bounds__(1024) void scan_kernel(
    int* __restrict__ deg, int* __restrict__ off, int N)
{
    __shared__ int sums[1024];
    const int tid = threadIdx.x;
    const int C = (N + 1023) >> 10;          // chunk per thread
    const int base = tid * C;
    int s = 0;
    for (int k = 0; k < C; ++k) { int idx = base + k; if (idx < N) s += deg[idx]; }
    sums[tid] = s;
    __syncthreads();
    for (int o = 1; o < 1024; o <<= 1) {
        int v = (tid >= o) ? sums[tid - o] : 0;
        __syncthreads();
        sums[tid] += v;
        __syncthreads();
    }
    int run = sums[tid] - s;                 // exclusive prefix of this chunk
    for (int k = 0; k < C; ++k) {
        int idx = base + k;
        if (idx < N) { int d = deg[idx]; off[idx] = run; deg[idx] = run; run += d; }
    }
    if (tid == 1023) off[N] = sums[1023];
}

__global__ __launch_bounds__(256) void fill_kernel(
    const int* __restrict__ eidx, int* __restrict__ cur, int* __restrict__ adj, int E)
{
    int i = blockIdx.x * 256 + threadIdx.x;
    if (i < 2 * E) {
        int n = eidx[i];
        int p = atomicAdd(&cur[n], 1);
        adj[p] = (i < E) ? i : i - E;        // edge id (endpoint identity irrelevant)
    }
}

// ---------------- edge pass 1 ----------------
// per block: 64 edges. GEMM1: [64,256]x[256,128] -> h = relu(.)
// row layout in edgebuf (aliases edge_out region, 512B per row):
//   bytes [0,256)  = h  in bf16 (consumed by node_kernel gather)
//   bytes [256,512)= b2 = (1+eps2)*h + lift in bf16 (consumed by edge_kernel2)
__global__ __launch_bounds__(256) void edge_kernel1(
    const float* __restrict__ node_rep, const float* __restrict__ edge_rep,
    const int* __restrict__ eidx, const short* __restrict__ W1T,
    const float* __restrict__ eps2p, char* __restrict__ edgebuf, int E)
{
    __shared__ short sA[MB * LDA];           // concat(lift, edge_rep) bf16; reused for h|b2

    const int tid = threadIdx.x;
    const int e0  = blockIdx.x * MB;
    const float e2 = 1.f + eps2p[0];

    // ---- stage: 4 threads per edge row, 32 cols each ----
    {
        int row  = tid >> 2;
        int cseg = (tid & 3) << 5;           // 0,32,64,96
        int e = e0 + row;
        short* rowA = sA + row * LDA;
        if (e < E) {
            int sIdx = eidx[e], dIdx = eidx[E + e];
            const float4* sp = (const float4*)(node_rep + (size_t)sIdx * H + cseg);
            const float4* dp = (const float4*)(node_rep + (size_t)dIdx * H + cseg);
            const float4* ep = (const float4*)(edge_rep + (size_t)e * H + cseg);
            #pragma unroll
            for (int j = 0; j < 8; ++j) {
                float4 a = sp[j], b = dp[j], c = ep[j];
                int cc = cseg + 4 * j;
                s16x4 lift = { f2bf(a.x + b.x), f2bf(a.y + b.y),
                               f2bf(a.z + b.z), f2bf(a.w + b.w) };
                s16x4 er   = { f2bf(c.x), f2bf(c.y), f2bf(c.z), f2bf(c.w) };
                *(s16x4*)&rowA[cc]     = lift;
                *(s16x4*)&rowA[H + cc] = er;
            }
        } else {
            s16x4 z = {0, 0, 0, 0};
            #pragma unroll
            for (int j = 0; j < 8; ++j) {
                int cc = cseg + 4 * j;
                *(s16x4*)&rowA[cc]     = z;
                *(s16x4*)&rowA[H + cc] = z;
            }
        }
    }
    __syncthreads();

    const int wave = tid >> 6;
    const int lane = tid & 63;
    const int m = lane & 15;     // D col
    const int q = lane >> 4;     // D row group

    f32x4 zero = {0.f, 0.f, 0.f, 0.f};
    f32x4 acc[4][2];
    #pragma unroll
    for (int mt = 0; mt < 4; ++mt)
        #pragma unroll
        for (int nt = 0; nt < 2; ++nt) acc[mt][nt] = zero;

    #pragma unroll
    for (int ks = 0; ks < 8; ++ks) {
        int k0 = ks * 32 + q * 8;
        bf16x8 aF[4];
        #pragma unroll
        for (int mt = 0; mt < 4; ++mt)
            aF[mt] = *(const bf16x8*)&sA[(mt * 16 + m) * LDA + k0];
        bf16x8 bF[2];
        #pragma unroll
        for (int nt = 0; nt < 2; ++nt) {
            int n = (wave << 5) + (nt << 4) + m;
            bF[nt] = *(const bf16x8*)&W1T[n * 256 + k0];
        }
        #pragma unroll
        for (int mt = 0; mt < 4; ++mt)
            #pragma unroll
            for (int nt = 0; nt < 2; ++nt)
                acc[mt][nt] = __builtin_amdgcn_mfma_f32_16x16x32_bf16(
                    aF[mt], bF[nt], acc[mt][nt], 0, 0, 0);
    }

    // ---- relu; compute b2 into regs (reads lift from sA) ----
    float b2v[4][2][4];
    #pragma unroll
    for (int mt = 0; mt < 4; ++mt) {
        #pragma unroll
        for (int nt = 0; nt < 2; ++nt) {
            int col = (wave << 5) + (nt << 4) + m;
            #pragma unroll
            for (int i = 0; i < 4; ++i) {
                int rr = (mt << 4) + (q << 2) + i;
                float h = acc[mt][nt][i];
                h = h > 0.f ? h : 0.f;
                acc[mt][nt][i] = h;
                b2v[mt][nt][i] = e2 * h + bf2f(sA[rr * LDA + col]);
            }
        }
    }
    __syncthreads();   // all lift reads done before sA is overwritten

    // ---- pack h | b2 into sA cols [0,256) ----
    #pragma unroll
    for (int mt = 0; mt < 4; ++mt) {
        #pragma unroll
        for (int nt = 0; nt < 2; ++nt) {
            int col = (wave << 5) + (nt << 4) + m;
            #pragma unroll
            for (int i = 0; i < 4; ++i) {
                int rr = (mt << 4) + (q << 2) + i;
                sA[rr * LDA + col]       = f2bf(acc[mt][nt][i]);
                sA[rr * LDA + 128 + col] = f2bf(b2v[mt][nt][i]);
            }
        }
    }
    __syncthreads();

    // ---- coalesced writeout: 512B per row ----
    {
        int row = tid >> 2, seg = tid & 3;
        int e = e0 + row;
        if (e < E) {
            const short* src = &sA[row * LDA + seg * 64];
            char* dst = edgebuf + (size_t)e * 512 + seg * 128;
            #pragma unroll
            for (int k = 0; k < 8; ++k)
                *(bf16x8*)(dst + k * 16) = *(const bf16x8*)(src + k * 8);
        }
    }
}

// ---------------- node kernel: CSR gather + GEMM ----------------
// one wave per node for aggregation (coalesced 256B read per incident edge),
// then the 64-row MFMA GEMM with W2.
__global__ __launch_bounds__(256) void node_kernel(
    const float* __restrict__ node_rep, const char* __restrict__ edgebuf,
    const int* __restrict__ off, const int* __restrict__ adj,
    const short* __restrict__ W2T, const float* __restrict__ eps1p,
    float* __restrict__ node_out, int N)
{
    __shared__ short sA[MB * LDB];

    const int tid  = threadIdx.x;
    const int n0   = blockIdx.x * MB;
    const int wave = tid >> 6;
    const int lane = tid & 63;
    const float e1 = 1.f + eps1p[0];

    for (int r = wave * 16; r < wave * 16 + 16; ++r) {
        int n = n0 + r;
        float a0 = 0.f, a1 = 0.f;
        if (n < N) {
            int d0 = off[n], d1 = off[n + 1];
            int j = d0;
            for (; j + 1 < d1; j += 2) {
                int ea = adj[j], eb = adj[j + 1];
                unsigned va = *(const unsigned*)(edgebuf + (size_t)ea * 512 + lane * 4);
                unsigned vb = *(const unsigned*)(edgebuf + (size_t)eb * 512 + lane * 4);
                a0 += bf2f((short)(va & 0xFFFF)) + bf2f((short)(vb & 0xFFFF));
                a1 += bf2f((short)(va >> 16))    + bf2f((short)(vb >> 16));
            }
            if (j < d1) {
                int ea = adj[j];
                unsigned va = *(const unsigned*)(edgebuf + (size_t)ea * 512 + lane * 4);
                a0 += bf2f((short)(va & 0xFFFF));
                a1 += bf2f((short)(va >> 16));
            }
            float2 nr = *(const float2*)(node_rep + (size_t)n * H + lane * 2);
            a0 = e1 * nr.x + a0;
            a1 = e1 * nr.y + a1;
        }
        s16x2 v = { f2bf(a0), f2bf(a1) };
        *(s16x2*)&sA[r * LDB + lane * 2] = v;
    }
    __syncthreads();

    const int m = lane & 15;
    const int q = lane >> 4;

    f32x4 zero = {0.f, 0.f, 0.f, 0.f};
    f32x4 acc[4][2];
    #pragma unroll
    for (int mt = 0; mt < 4; ++mt)
        #pragma unroll
        for (int nt = 0; nt < 2; ++nt) acc[mt][nt] = zero;

    #pragma unroll
    for (int ks = 0; ks < 4; ++ks) {
        int k0 = ks * 32 + q * 8;
        bf16x8 aF[4];
        #pragma unroll
        for (int mt = 0; mt < 4; ++mt)
            aF[mt] = *(const bf16x8*)&sA[(mt * 16 + m) * LDB + k0];
        bf16x8 bF[2];
        #pragma unroll
        for (int nt = 0; nt < 2; ++nt) {
            int n = (wave << 5) + (nt << 4) + m;
            bF[nt] = *(const bf16x8*)&W2T[n * 128 + k0];
        }
        #pragma unroll
        for (int mt = 0; mt < 4; ++mt)
            #pragma unroll
            for (int nt = 0; nt < 2; ++nt)
                acc[mt][nt] = __builtin_amdgcn_mfma_f32_16x16x32_bf16(
                    aF[mt], bF[nt], acc[mt][nt], 0, 0, 0);
    }

    #pragma unroll
    for (int mt = 0; mt < 4; ++mt) {
        #pragma unroll
        for (int nt = 0; nt < 2; ++nt) {
            int col = (wave << 5) + (nt << 4) + m;
            #pragma unroll
            for (int i = 0; i < 4; ++i) {
                int rr = (mt << 4) + (q << 2) + i;
                if (n0 + rr < N) {
                    float v = acc[mt][nt][i];
                    node_out[(size_t)(n0 + rr) * H + col] = v > 0.f ? v : 0.f;
                }
            }
        }
    }
}

// ---------------- edge pass 2: edge_out = relu(b2 @ W_lift), in place ----------------
// block reads the b2 halves of its OWN 64 rows into LDS, then overwrites those
// same rows with fp32 output — no cross-block hazard.
__global__ __launch_bounds__(256) void edge_kernel2(
    const short* __restrict__ WLT, char* edgebuf, int E)
{
    __shared__ short sB[MB * LDB];
    float* edge_out = (float*)edgebuf;

    const int tid = threadIdx.x;
    const int e0  = blockIdx.x * MB;

    {
        int row = tid >> 2, seg = tid & 3;
        int e = e0 + row;
        short* dst = &sB[row * LDB + seg * 32];
        if (e < E) {
            const char* src = edgebuf + (size_t)e * 512 + 256 + seg * 64;
            #pragma unroll
            for (int k = 0; k < 4; ++k)
                *(bf16x8*)(dst + k * 8) = *(const bf16x8*)(src + k * 16);
        } else {
            bf16x8 z = {0, 0, 0, 0, 0, 0, 0, 0};
            #pragma unroll
            for (int k = 0; k < 4; ++k) *(bf16x8*)(dst + k * 8) = z;
        }
    }
    __syncthreads();

    const int wave = tid >> 6;
    const int lane = tid & 63;
    const int m = lane & 15;
    const int q = lane >> 4;

    f32x4 zero = {0.f, 0.f, 0.f, 0.f};
    f32x4 acc2[4][2];
    #pragma unroll
    for (int mt = 0; mt < 4; ++mt)
        #pragma unroll
        for (int nt = 0; nt < 2; ++nt) acc2[mt][nt] = zero;

    #pragma unroll
    for (int ks = 0; ks < 4; ++ks) {
        int k0 = ks * 32 + q * 8;
        bf16x8 aF[4];
        #pragma unroll
        for (int mt = 0; mt < 4; ++mt)
            aF[mt] = *(const bf16x8*)&sB[(mt * 16 + m) * LDB + k0];
        bf16x8 bF[2];
        #pragma unroll
        for (int nt = 0; nt < 2; ++nt) {
            int n = (wave << 5) + (nt << 4) + m;
            bF[nt] = *(const bf16x8*)&WLT[n * 128 + k0];
        }
        #pragma unroll
        for (int mt = 0; mt < 4; ++mt)
            #pragma unroll
            for (int nt = 0; nt < 2; ++nt)
                acc2[mt][nt] = __builtin_amdgcn_mfma_f32_16x16x32_bf16(
                    aF[mt], bF[nt], acc2[mt][nt], 0, 0, 0);
    }

    #pragma unroll
    for (int mt = 0; mt < 4; ++mt) {
        #pragma unroll
        for (int nt = 0; nt < 2; ++nt) {
            int col = (wave << 5) + (nt << 4) + m;
            #pragma unroll
            for (int i = 0; i < 4; ++i) {
                int rr = (mt << 4) + (q << 2) + i;
                if (e0 + rr < E) {
                    float v = acc2[mt][nt][i];
                    edge_out[(size_t)(e0 + rr) * H + col] = v > 0.f ? v : 0.f;
                }
            }
        }
    }
}

extern "C" void kernel_launch(void* const* d_in, const int* in_sizes, int n_in,
                              void* d_out, int out_size, void* d_ws, size_t ws_size,
                              hipStream_t stream) {
    const float* node_rep = (const float*)d_in[0];
    const float* edge_rep = (const float*)d_in[1];
    const int*   eidx     = (const int*)d_in[2];
    const float* W1       = (const float*)d_in[3];
    const float* W2       = (const float*)d_in[4];
    const float* WL       = (const float*)d_in[5];
    const float* eps1     = (const float*)d_in[6];
    const float* eps2     = (const float*)d_in[7];

    const int N = in_sizes[0] / H;     // 50000
    const int E = in_sizes[1] / H;     // 800000

    float* node_out = (float*)d_out;
    // edge_out region doubles as the bf16 h|b2 staging buffer (512B per row).
    char* edgebuf = (char*)d_out + (size_t)N * H * sizeof(float);

    // workspace layout: bf16 weights (128KB) + CSR arrays (~6.9MB total)
    char* ws = (char*)d_ws;
    short* W1T = (short*)ws;                       // 256*128*2 = 64 KB
    short* W2T = (short*)(ws + 65536);             // 32 KB
    short* WLT = (short*)(ws + 65536 + 32768);     // 32 KB
    size_t o_deg = 131072;
    size_t o_off = o_deg + sizeof(int) * (size_t)N;
    size_t o_adj = (o_off + sizeof(int) * (size_t)(N + 1) + 255) & ~(size_t)255;
    int* deg = (int*)(ws + o_deg);                 // becomes fill cursor after scan
    int* off = (int*)(ws + o_off);
    int* adj = (int*)(ws + o_adj);                 // 2E ints = 6.4 MB

    const int M2 = 2 * E;

    hipMemsetAsync(deg, 0, sizeof(int) * (size_t)N, stream);
    prep_weights<<<128, 256, 0, stream>>>(W1, W2, WL, W1T, W2T, WLT);
    hist_kernel<<<(M2 + 255) / 256, 256, 0, stream>>>(eidx, deg, M2);
    scan_kernel<<<1, 1024, 0, stream>>>(deg, off, N);
    fill_kernel<<<(M2 + 255) / 256, 256, 0, stream>>>(eidx, deg, adj, E);
    edge_kernel1<<<(E + MB - 1) / MB, 256, 0, stream>>>(
        node_rep, edge_rep, eidx, W1T, eps2, edgebuf, E);
    node_kernel<<<(N + MB - 1) / MB, 256, 0, stream>>>(
        node_rep, edgebuf, off, adj, W2T, eps1, node_out, N);
    edge_kernel2<<<(E + MB - 1) / MB, 256, 0, stream>>>(WLT, edgebuf, E);
}

// Round 2
// 830.551 us; speedup vs baseline: 1.3772x; 1.3772x over previous
//
#include <hip/hip_runtime.h>

#define H 128
#define MB 64          // edges (or nodes) per block
#define LDA 264        // LDS row stride (elems) for the [64 x 256] concat tile (+8 pad)
#define LDB 136        // LDS row stride for [64 x 128] tiles (+8 pad)

typedef __attribute__((ext_vector_type(8))) short bf16x8;
typedef __attribute__((ext_vector_type(4))) short s16x4;
typedef __attribute__((ext_vector_type(4))) float f32x4;

__device__ __forceinline__ short f2bf(float f) {
    union { float f; unsigned u; } v; v.f = f;
    unsigned r = v.u + 0x7FFF + ((v.u >> 16) & 1);   // RTNE
    return (short)(r >> 16);
}
__device__ __forceinline__ float bf2f(short s) {
    union { unsigned u; float f; } v;
    v.u = ((unsigned)(unsigned short)s) << 16;
    return v.f;
}
__device__ __forceinline__ unsigned short f2h(float f) {
    union { _Float16 h; unsigned short u; } c;
    c.h = (_Float16)f;                               // v_cvt_f16_f32 (RTNE)
    return c.u;
}
__device__ __forceinline__ float h2f(unsigned short u) {
    union { unsigned short u; _Float16 h; } c;
    c.u = u;
    return (float)c.h;                               // v_cvt_f32_f16
}

// ---------------- weight prep: fp32 [K,N] -> bf16 transposed [N,K] ----------------
__global__ __launch_bounds__(256) void prep_weights(
    const float* __restrict__ W1, const float* __restrict__ W2,
    const float* __restrict__ WL,
    short* __restrict__ W1T, short* __restrict__ W2T, short* __restrict__ WLT)
{
    int tid = blockIdx.x * 256 + threadIdx.x;      // 0..32767
    {   // W1: [256,128] -> W1T [128][256]
        int n = tid >> 8, k = tid & 255;
        W1T[n * 256 + k] = f2bf(W1[k * 128 + n]);
    }
    if (tid < 16384) {  // W2, W_lift: [128,128] -> [128][128]
        int n = tid >> 7, k = tid & 127;
        W2T[n * 128 + k] = f2bf(W2[k * 128 + n]);
        WLT[n * 128 + k] = f2bf(WL[k * 128 + n]);
    }
}

// ---------------- edge kernel ----------------
// per block: 64 edges.  GEMM1: [64,256]x[256,128]; GEMM2: [64,128]x[128,128];
// then deferred scatter of h into fp16 lvl via packed-f16 atomics (2 elems / op).
__global__ __launch_bounds__(256) void edge_kernel(
    const float* __restrict__ node_rep, const float* __restrict__ edge_rep,
    const int* __restrict__ eidx,
    const short* __restrict__ W1T, const short* __restrict__ WLT,
    const float* __restrict__ eps2p,
    unsigned short* __restrict__ lvl, float* __restrict__ edge_out, int E)
{
    __shared__ short sA[MB * LDA];   // concat(lift, edge_rep) bf16
    __shared__ short sB[MB * LDB];   // B2 tile bf16
    __shared__ int sSrc[MB], sDst[MB];

    const int tid = threadIdx.x;
    const int e0  = blockIdx.x * MB;
    const float e2 = 1.f + eps2p[0];

    // ---- stage: 4 threads per edge row, each covers 32 cols ----
    {
        int row  = tid >> 2;
        int cseg = (tid & 3) << 5;        // 0,32,64,96
        int e = e0 + row;
        int sIdx = 0, dIdx = 0;
        bool ev = (e < E);
        if (ev) { sIdx = eidx[e]; dIdx = eidx[E + e]; }
        if ((tid & 3) == 0) { sSrc[row] = sIdx; sDst[row] = dIdx; }
        short* rowA = sA + row * LDA;
        if (ev) {
            const float4* sp = (const float4*)(node_rep + (size_t)sIdx * H + cseg);
            const float4* dp = (const float4*)(node_rep + (size_t)dIdx * H + cseg);
            const float4* ep = (const float4*)(edge_rep + (size_t)e * H + cseg);
            #pragma unroll
            for (int j = 0; j < 8; ++j) {
                float4 a = sp[j], b = dp[j], c = ep[j];
                int cc = cseg + 4 * j;
                s16x4 lift = { f2bf(a.x + b.x), f2bf(a.y + b.y),
                               f2bf(a.z + b.z), f2bf(a.w + b.w) };
                s16x4 er   = { f2bf(c.x), f2bf(c.y), f2bf(c.z), f2bf(c.w) };
                *(s16x4*)&rowA[cc]      = lift;
                *(s16x4*)&rowA[H + cc]  = er;
            }
        } else {
            s16x4 z = {0, 0, 0, 0};
            #pragma unroll
            for (int j = 0; j < 8; ++j) {
                int cc = cseg + 4 * j;
                *(s16x4*)&rowA[cc]     = z;
                *(s16x4*)&rowA[H + cc] = z;
            }
        }
    }
    __syncthreads();

    const int wave = tid >> 6;
    const int lane = tid & 63;
    const int m = lane & 15;     // A row / B col / D col
    const int q = lane >> 4;     // k-quad, D row group

    // ---- GEMM1: wave owns cols [wave*32, wave*32+32), all 64 rows ----
    f32x4 zero = {0.f, 0.f, 0.f, 0.f};
    f32x4 acc[4][2];
    #pragma unroll
    for (int mt = 0; mt < 4; ++mt)
        #pragma unroll
        for (int nt = 0; nt < 2; ++nt) acc[mt][nt] = zero;

    #pragma unroll
    for (int ks = 0; ks < 8; ++ks) {
        int k0 = ks * 32 + q * 8;
        bf16x8 aF[4];
        #pragma unroll
        for (int mt = 0; mt < 4; ++mt)
            aF[mt] = *(const bf16x8*)&sA[(mt * 16 + m) * LDA + k0];
        bf16x8 bF[2];
        #pragma unroll
        for (int nt = 0; nt < 2; ++nt) {
            int n = (wave << 5) + (nt << 4) + m;
            bF[nt] = *(const bf16x8*)&W1T[n * 256 + k0];
        }
        #pragma unroll
        for (int mt = 0; mt < 4; ++mt)
            #pragma unroll
            for (int nt = 0; nt < 2; ++nt)
                acc[mt][nt] = __builtin_amdgcn_mfma_f32_16x16x32_bf16(
                    aF[mt], bF[nt], acc[mt][nt], 0, 0, 0);
    }

    // ---- epilogue 1: relu (keep h in acc), build B2 tile in LDS ----
    #pragma unroll
    for (int mt = 0; mt < 4; ++mt) {
        #pragma unroll
        for (int nt = 0; nt < 2; ++nt) {
            int col = (wave << 5) + (nt << 4) + m;
            #pragma unroll
            for (int i = 0; i < 4; ++i) {
                int rr = (mt << 4) + (q << 2) + i;
                float h = acc[mt][nt][i];
                h = h > 0.f ? h : 0.f;
                acc[mt][nt][i] = h;
                if (e0 + rr < E) {
                    float b2 = e2 * h + bf2f(sA[rr * LDA + col]);
                    sB[rr * LDB + col] = f2bf(b2);
                }
            }
        }
    }
    __syncthreads();

    // ---- GEMM2: edge_out = relu(B2 @ W_lift) ----
    f32x4 acc2[4][2];
    #pragma unroll
    for (int mt = 0; mt < 4; ++mt)
        #pragma unroll
        for (int nt = 0; nt < 2; ++nt) acc2[mt][nt] = zero;

    #pragma unroll
    for (int ks = 0; ks < 4; ++ks) {
        int k0 = ks * 32 + q * 8;
        bf16x8 aF[4];
        #pragma unroll
        for (int mt = 0; mt < 4; ++mt)
            aF[mt] = *(const bf16x8*)&sB[(mt * 16 + m) * LDB + k0];
        bf16x8 bF[2];
        #pragma unroll
        for (int nt = 0; nt < 2; ++nt) {
            int n = (wave << 5) + (nt << 4) + m;
            bF[nt] = *(const bf16x8*)&WLT[n * 128 + k0];
        }
        #pragma unroll
        for (int mt = 0; mt < 4; ++mt)
            #pragma unroll
            for (int nt = 0; nt < 2; ++nt)
                acc2[mt][nt] = __builtin_amdgcn_mfma_f32_16x16x32_bf16(
                    aF[mt], bF[nt], acc2[mt][nt], 0, 0, 0);
    }

    #pragma unroll
    for (int mt = 0; mt < 4; ++mt) {
        #pragma unroll
        for (int nt = 0; nt < 2; ++nt) {
            int col = (wave << 5) + (nt << 4) + m;
            #pragma unroll
            for (int i = 0; i < 4; ++i) {
                int rr = (mt << 4) + (q << 2) + i;
                if (e0 + rr < E) {
                    float v = acc2[mt][nt][i];
                    edge_out[(size_t)(e0 + rr) * H + col] = v > 0.f ? v : 0.f;
                }
            }
        }
    }

    // ---- deferred scatter: packed fp16 atomics (2 elems / 4B op) ----
    // Lanes m and m^1 hold adjacent cols of the same rows; even lanes issue.
    #pragma unroll
    for (int mt = 0; mt < 4; ++mt) {
        #pragma unroll
        for (int nt = 0; nt < 2; ++nt) {
            int col = (wave << 5) + (nt << 4) + m;
            #pragma unroll
            for (int i = 0; i < 4; ++i) {
                int rr = (mt << 4) + (q << 2) + i;
                float v  = acc[mt][nt][i];
                float vn = __shfl_xor(v, 1);
                if ((m & 1) == 0 && e0 + rr < E) {
                    unsigned pk = (unsigned)f2h(v) | ((unsigned)f2h(vn) << 16);
                    int sn = sSrc[rr], dn = sDst[rr];
                    unsigned long long a0 =
                        (unsigned long long)(lvl + (size_t)sn * H + col);
                    unsigned long long a1 =
                        (unsigned long long)(lvl + (size_t)dn * H + col);
                    asm volatile("global_atomic_pk_add_f16 %0, %1, off"
                                 :: "v"(a0), "v"(pk) : "memory");
                    asm volatile("global_atomic_pk_add_f16 %0, %1, off"
                                 :: "v"(a1), "v"(pk) : "memory");
                }
            }
        }
    }
}

// ---------------- node kernel ----------------
// node_out = relu(((1+eps1)*node_rep + lvl_fp16) @ W2)
__global__ __launch_bounds__(256) void node_kernel(
    const float* __restrict__ node_rep, const unsigned short* __restrict__ lvl,
    const short* __restrict__ W2T, const float* __restrict__ eps1p,
    float* __restrict__ node_out, int N)
{
    __shared__ short sA[MB * LDB];

    const int tid = threadIdx.x;
    const int r0  = blockIdx.x * MB;
    const float e1 = 1.f + eps1p[0];

    {
        int row  = tid >> 2;
        int cseg = (tid & 3) << 5;
        int r = r0 + row;
        short* rowA = sA + row * LDB;
        if (r < N) {
            const float4* np = (const float4*)(node_rep + (size_t)r * H + cseg);
            const unsigned short* lp = lvl + (size_t)r * H + cseg;
            #pragma unroll
            for (int j = 0; j < 8; ++j) {
                float4 a = np[j];
                uint2 hv = *(const uint2*)(lp + 4 * j);
                float f0 = h2f((unsigned short)(hv.x & 0xFFFF));
                float f1 = h2f((unsigned short)(hv.x >> 16));
                float f2 = h2f((unsigned short)(hv.y & 0xFFFF));
                float f3 = h2f((unsigned short)(hv.y >> 16));
                int cc = cseg + 4 * j;
                s16x4 v = { f2bf(e1 * a.x + f0), f2bf(e1 * a.y + f1),
                            f2bf(e1 * a.z + f2), f2bf(e1 * a.w + f3) };
                *(s16x4*)&rowA[cc] = v;
            }
        } else {
            s16x4 z = {0, 0, 0, 0};
            #pragma unroll
            for (int j = 0; j < 8; ++j) *(s16x4*)&rowA[cseg + 4 * j] = z;
        }
    }
    __syncthreads();

    const int wave = tid >> 6;
    const int lane = tid & 63;
    const int m = lane & 15;
    const int q = lane >> 4;

    f32x4 zero = {0.f, 0.f, 0.f, 0.f};
    f32x4 acc[4][2];
    #pragma unroll
    for (int mt = 0; mt < 4; ++mt)
        #pragma unroll
        for (int nt = 0; nt < 2; ++nt) acc[mt][nt] = zero;

    #pragma unroll
    for (int ks = 0; ks < 4; ++ks) {
        int k0 = ks * 32 + q * 8;
        bf16x8 aF[4];
        #pragma unroll
        for (int mt = 0; mt < 4; ++mt)
            aF[mt] = *(const bf16x8*)&sA[(mt * 16 + m) * LDB + k0];
        bf16x8 bF[2];
        #pragma unroll
        for (int nt = 0; nt < 2; ++nt) {
            int n = (wave << 5) + (nt << 4) + m;
            bF[nt] = *(const bf16x8*)&W2T[n * 128 + k0];
        }
        #pragma unroll
        for (int mt = 0; mt < 4; ++mt)
            #pragma unroll
            for (int nt = 0; nt < 2; ++nt)
                acc[mt][nt] = __builtin_amdgcn_mfma_f32_16x16x32_bf16(
                    aF[mt], bF[nt], acc[mt][nt], 0, 0, 0);
    }

    #pragma unroll
    for (int mt = 0; mt < 4; ++mt) {
        #pragma unroll
        for (int nt = 0; nt < 2; ++nt) {
            int col = (wave << 5) + (nt << 4) + m;
            #pragma unroll
            for (int i = 0; i < 4; ++i) {
                int rr = (mt << 4) + (q << 2) + i;
                if (r0 + rr < N) {
                    float v = acc[mt][nt][i];
                    node_out[(size_t)(r0 + rr) * H + col] = v > 0.f ? v : 0.f;
                }
            }
        }
    }
}

extern "C" void kernel_launch(void* const* d_in, const int* in_sizes, int n_in,
                              void* d_out, int out_size, void* d_ws, size_t ws_size,
                              hipStream_t stream) {
    const float* node_rep = (const float*)d_in[0];
    const float* edge_rep = (const float*)d_in[1];
    const int*   eidx     = (const int*)d_in[2];
    const float* W1       = (const float*)d_in[3];
    const float* W2       = (const float*)d_in[4];
    const float* WL       = (const float*)d_in[5];
    const float* eps1     = (const float*)d_in[6];
    const float* eps2     = (const float*)d_in[7];

    const int N = in_sizes[0] / H;     // 50000
    const int E = in_sizes[1] / H;     // 800000

    float* node_out = (float*)d_out;
    float* edge_out = (float*)d_out + (size_t)N * H;

    // workspace: bf16 weights (128 KB) + fp16 lvl accumulator (12.8 MB)
    char* ws = (char*)d_ws;
    short* W1T = (short*)ws;                               // 256*128*2 = 64 KB
    short* W2T = (short*)(ws + 65536);                     // 32 KB
    short* WLT = (short*)(ws + 65536 + 32768);             // 32 KB
    unsigned short* lvl = (unsigned short*)(ws + 131072);  // N*H*2 = 12.8 MB

    hipMemsetAsync(lvl, 0, (size_t)N * H * sizeof(unsigned short), stream);
    prep_weights<<<128, 256, 0, stream>>>(W1, W2, WL, W1T, W2T, WLT);
    edge_kernel<<<(E + MB - 1) / MB, 256, 0, stream>>>(
        node_rep, edge_rep, eidx, W1T, WLT, eps2, lvl, edge_out, E);
    node_kernel<<<(N + MB - 1) / MB, 256, 0, stream>>>(
        node_rep, lvl, W2T, eps1, node_out, N);
}

// Round 3
// 770.315 us; speedup vs baseline: 1.4849x; 1.0782x over previous
//
#include <hip/hip_runtime.h>

#define H 128
#define MB 64          // edges (or nodes) per block
#define LDA 264        // LDS row stride (elems) for the [64 x 256] concat tile (+8 pad)
#define LDB 136        // LDS row stride for [64 x 128] tiles (+8 pad)

typedef __attribute__((ext_vector_type(8))) short bf16x8;
typedef __attribute__((ext_vector_type(4))) short s16x4;
typedef __attribute__((ext_vector_type(4))) float f32x4;

__device__ __forceinline__ short f2bf(float f) {
    union { float f; unsigned u; } v; v.f = f;
    unsigned r = v.u + 0x7FFF + ((v.u >> 16) & 1);   // RTNE
    return (short)(r >> 16);
}
__device__ __forceinline__ float bf2f(short s) {
    union { unsigned u; float f; } v;
    v.u = ((unsigned)(unsigned short)s) << 16;
    return v.f;
}
__device__ __forceinline__ unsigned short f2h(float f) {
    union { _Float16 h; unsigned short u; } c;
    c.h = (_Float16)f;                               // v_cvt_f16_f32 (RTNE)
    return c.u;
}
__device__ __forceinline__ float h2f(unsigned short u) {
    union { unsigned short u; _Float16 h; } c;
    c.u = u;
    return (float)c.h;                               // v_cvt_f32_f16
}

// ---------------- weight prep: fp32 [K,N] -> bf16 transposed [N,K] ----------------
__global__ __launch_bounds__(256) void prep_weights(
    const float* __restrict__ W1, const float* __restrict__ W2,
    const float* __restrict__ WL,
    short* __restrict__ W1T, short* __restrict__ W2T, short* __restrict__ WLT)
{
    int tid = blockIdx.x * 256 + threadIdx.x;      // 0..32767
    {   // W1: [256,128] -> W1T [128][256]
        int n = tid >> 8, k = tid & 255;
        W1T[n * 256 + k] = f2bf(W1[k * 128 + n]);
    }
    if (tid < 16384) {  // W2, W_lift: [128,128] -> [128][128]
        int n = tid >> 7, k = tid & 127;
        W2T[n * 128 + k] = f2bf(W2[k * 128 + n]);
        WLT[n * 128 + k] = f2bf(WL[k * 128 + n]);
    }
}

// ---------------- node_rep fp32 -> bf16 copy (halves gather traffic) ----------------
__global__ __launch_bounds__(256) void node_prep(
    const float* __restrict__ node_rep, short* __restrict__ NRB, int total8)
{
    int i = blockIdx.x * 256 + threadIdx.x;        // one per 8 elems
    if (i < total8) {
        const float4* p = (const float4*)(node_rep + (size_t)i * 8);
        float4 a = p[0], b = p[1];
        bf16x8 o = { f2bf(a.x), f2bf(a.y), f2bf(a.z), f2bf(a.w),
                     f2bf(b.x), f2bf(b.y), f2bf(b.z), f2bf(b.w) };
        *(bf16x8*)(NRB + (size_t)i * 8) = o;
    }
}

// ---------------- edge kernel ----------------
// per block: 64 edges.  GEMM1: [64,256]x[256,128]; GEMM2 on b2 written into the
// (dead after GEMM1) edge_rep half of sA; deferred packed-fp16 atomic scatter.
__global__ __launch_bounds__(256) void edge_kernel(
    const short* __restrict__ NRB, const float* __restrict__ edge_rep,
    const int* __restrict__ eidx,
    const short* __restrict__ W1T, const short* __restrict__ WLT,
    const float* __restrict__ eps2p,
    unsigned short* __restrict__ lvl, float* __restrict__ edge_out, int E)
{
    __shared__ short sA[MB * LDA];   // [64][256]: cols 0..127 lift, 128..255 edge_rep -> b2
    __shared__ int sSrc[MB], sDst[MB];

    const int tid = threadIdx.x;
    const int e0  = blockIdx.x * MB;
    const float e2 = 1.f + eps2p[0];

    // ---- stage: 4 threads per edge row, each covers 32 cols ----
    {
        int row  = tid >> 2;
        int cseg = (tid & 3) << 5;        // 0,32,64,96
        int e = e0 + row;
        int sIdx = 0, dIdx = 0;
        bool ev = (e < E);
        if (ev) { sIdx = eidx[e]; dIdx = eidx[E + e]; }
        if ((tid & 3) == 0) { sSrc[row] = sIdx; sDst[row] = dIdx; }
        short* rowA = sA + row * LDA;
        if (ev) {
            const bf16x8* sp = (const bf16x8*)(NRB + (size_t)sIdx * H + cseg);
            const bf16x8* dp = (const bf16x8*)(NRB + (size_t)dIdx * H + cseg);
            const float4* ep = (const float4*)(edge_rep + (size_t)e * H + cseg);
            #pragma unroll
            for (int j = 0; j < 4; ++j) {
                bf16x8 a = sp[j], b = dp[j];
                bf16x8 lift;
                #pragma unroll
                for (int t = 0; t < 8; ++t)
                    lift[t] = f2bf(bf2f(a[t]) + bf2f(b[t]));
                *(bf16x8*)&rowA[cseg + 8 * j] = lift;
            }
            #pragma unroll
            for (int j = 0; j < 8; ++j) {
                float4 c = ep[j];
                s16x4 er = { f2bf(c.x), f2bf(c.y), f2bf(c.z), f2bf(c.w) };
                *(s16x4*)&rowA[H + cseg + 4 * j] = er;
            }
        } else {
            s16x4 z = {0, 0, 0, 0};
            #pragma unroll
            for (int j = 0; j < 8; ++j) {
                int cc = cseg + 4 * j;
                *(s16x4*)&rowA[cc]     = z;
                *(s16x4*)&rowA[H + cc] = z;
            }
        }
    }
    __syncthreads();

    const int wave = tid >> 6;
    const int lane = tid & 63;
    const int m = lane & 15;     // A row / B col / D col
    const int q = lane >> 4;     // k-quad, D row group

    // ---- GEMM1: wave owns cols [wave*32, wave*32+32), all 64 rows ----
    f32x4 zero = {0.f, 0.f, 0.f, 0.f};
    f32x4 acc[4][2];
    #pragma unroll
    for (int mt = 0; mt < 4; ++mt)
        #pragma unroll
        for (int nt = 0; nt < 2; ++nt) acc[mt][nt] = zero;

    #pragma unroll
    for (int ks = 0; ks < 8; ++ks) {
        int k0 = ks * 32 + q * 8;
        bf16x8 aF[4];
        #pragma unroll
        for (int mt = 0; mt < 4; ++mt)
            aF[mt] = *(const bf16x8*)&sA[(mt * 16 + m) * LDA + k0];
        bf16x8 bF[2];
        #pragma unroll
        for (int nt = 0; nt < 2; ++nt) {
            int n = (wave << 5) + (nt << 4) + m;
            bF[nt] = *(const bf16x8*)&W1T[n * 256 + k0];
        }
        #pragma unroll
        for (int mt = 0; mt < 4; ++mt)
            #pragma unroll
            for (int nt = 0; nt < 2; ++nt)
                acc[mt][nt] = __builtin_amdgcn_mfma_f32_16x16x32_bf16(
                    aF[mt], bF[nt], acc[mt][nt], 0, 0, 0);
    }
    __syncthreads();   // GEMM1 reads of cols 128..255 done before b2 overwrites them

    // ---- epilogue 1: relu (keep h in acc), write b2 into sA cols 128..255 ----
    #pragma unroll
    for (int mt = 0; mt < 4; ++mt) {
        #pragma unroll
        for (int nt = 0; nt < 2; ++nt) {
            int col = (wave << 5) + (nt << 4) + m;
            #pragma unroll
            for (int i = 0; i < 4; ++i) {
                int rr = (mt << 4) + (q << 2) + i;
                float h = acc[mt][nt][i];
                h = h > 0.f ? h : 0.f;
                acc[mt][nt][i] = h;
                float b2 = e2 * h + bf2f(sA[rr * LDA + col]);
                sA[rr * LDA + 128 + col] = f2bf(b2);
            }
        }
    }
    __syncthreads();

    // ---- GEMM2: edge_out = relu(B2 @ W_lift) ----
    f32x4 acc2[4][2];
    #pragma unroll
    for (int mt = 0; mt < 4; ++mt)
        #pragma unroll
        for (int nt = 0; nt < 2; ++nt) acc2[mt][nt] = zero;

    #pragma unroll
    for (int ks = 0; ks < 4; ++ks) {
        int k0 = ks * 32 + q * 8;
        bf16x8 aF[4];
        #pragma unroll
        for (int mt = 0; mt < 4; ++mt)
            aF[mt] = *(const bf16x8*)&sA[(mt * 16 + m) * LDA + 128 + k0];
        bf16x8 bF[2];
        #pragma unroll
        for (int nt = 0; nt < 2; ++nt) {
            int n = (wave << 5) + (nt << 4) + m;
            bF[nt] = *(const bf16x8*)&WLT[n * 128 + k0];
        }
        #pragma unroll
        for (int mt = 0; mt < 4; ++mt)
            #pragma unroll
            for (int nt = 0; nt < 2; ++nt)
                acc2[mt][nt] = __builtin_amdgcn_mfma_f32_16x16x32_bf16(
                    aF[mt], bF[nt], acc2[mt][nt], 0, 0, 0);
    }

    #pragma unroll
    for (int mt = 0; mt < 4; ++mt) {
        #pragma unroll
        for (int nt = 0; nt < 2; ++nt) {
            int col = (wave << 5) + (nt << 4) + m;
            #pragma unroll
            for (int i = 0; i < 4; ++i) {
                int rr = (mt << 4) + (q << 2) + i;
                if (e0 + rr < E) {
                    float v = acc2[mt][nt][i];
                    edge_out[(size_t)(e0 + rr) * H + col] = v > 0.f ? v : 0.f;
                }
            }
        }
    }

    // ---- deferred scatter: packed fp16 atomics (2 elems / 4B op) ----
    // Lanes m and m^1 hold adjacent cols of the same rows; even lanes issue.
    #pragma unroll
    for (int mt = 0; mt < 4; ++mt) {
        #pragma unroll
        for (int nt = 0; nt < 2; ++nt) {
            int col = (wave << 5) + (nt << 4) + m;
            #pragma unroll
            for (int i = 0; i < 4; ++i) {
                int rr = (mt << 4) + (q << 2) + i;
                float v  = acc[mt][nt][i];
                float vn = __shfl_xor(v, 1);
                if ((m & 1) == 0 && e0 + rr < E) {
                    unsigned pk = (unsigned)f2h(v) | ((unsigned)f2h(vn) << 16);
                    int sn = sSrc[rr], dn = sDst[rr];
                    unsigned long long a0 =
                        (unsigned long long)(lvl + (size_t)sn * H + col);
                    unsigned long long a1 =
                        (unsigned long long)(lvl + (size_t)dn * H + col);
                    asm volatile("global_atomic_pk_add_f16 %0, %1, off"
                                 :: "v"(a0), "v"(pk) : "memory");
                    asm volatile("global_atomic_pk_add_f16 %0, %1, off"
                                 :: "v"(a1), "v"(pk) : "memory");
                }
            }
        }
    }
}

// ---------------- node kernel ----------------
// node_out = relu(((1+eps1)*node_rep_bf16 + lvl_fp16) @ W2)
__global__ __launch_bounds__(256) void node_kernel(
    const short* __restrict__ NRB, const unsigned short* __restrict__ lvl,
    const short* __restrict__ W2T, const float* __restrict__ eps1p,
    float* __restrict__ node_out, int N)
{
    __shared__ short sA[MB * LDB];

    const int tid = threadIdx.x;
    const int r0  = blockIdx.x * MB;
    const float e1 = 1.f + eps1p[0];

    {
        int row  = tid >> 2;
        int cseg = (tid & 3) << 5;
        int r = r0 + row;
        short* rowA = sA + row * LDB;
        if (r < N) {
            const bf16x8* np = (const bf16x8*)(NRB + (size_t)r * H + cseg);
            const uint2* lp = (const uint2*)(lvl + (size_t)r * H + cseg);
            #pragma unroll
            for (int j = 0; j < 4; ++j) {
                bf16x8 nb = np[j];
                uint2 h0 = lp[2 * j], h1 = lp[2 * j + 1];
                float f[8] = {
                    h2f((unsigned short)(h0.x & 0xFFFF)), h2f((unsigned short)(h0.x >> 16)),
                    h2f((unsigned short)(h0.y & 0xFFFF)), h2f((unsigned short)(h0.y >> 16)),
                    h2f((unsigned short)(h1.x & 0xFFFF)), h2f((unsigned short)(h1.x >> 16)),
                    h2f((unsigned short)(h1.y & 0xFFFF)), h2f((unsigned short)(h1.y >> 16)) };
                bf16x8 o;
                #pragma unroll
                for (int t = 0; t < 8; ++t)
                    o[t] = f2bf(e1 * bf2f(nb[t]) + f[t]);
                *(bf16x8*)&rowA[cseg + 8 * j] = o;
            }
        } else {
            s16x4 z = {0, 0, 0, 0};
            #pragma unroll
            for (int j = 0; j < 8; ++j) *(s16x4*)&rowA[cseg + 4 * j] = z;
        }
    }
    __syncthreads();

    const int wave = tid >> 6;
    const int lane = tid & 63;
    const int m = lane & 15;
    const int q = lane >> 4;

    f32x4 zero = {0.f, 0.f, 0.f, 0.f};
    f32x4 acc[4][2];
    #pragma unroll
    for (int mt = 0; mt < 4; ++mt)
        #pragma unroll
        for (int nt = 0; nt < 2; ++nt) acc[mt][nt] = zero;

    #pragma unroll
    for (int ks = 0; ks < 4; ++ks) {
        int k0 = ks * 32 + q * 8;
        bf16x8 aF[4];
        #pragma unroll
        for (int mt = 0; mt < 4; ++mt)
            aF[mt] = *(const bf16x8*)&sA[(mt * 16 + m) * LDB + k0];
        bf16x8 bF[2];
        #pragma unroll
        for (int nt = 0; nt < 2; ++nt) {
            int n = (wave << 5) + (nt << 4) + m;
            bF[nt] = *(const bf16x8*)&W2T[n * 128 + k0];
        }
        #pragma unroll
        for (int mt = 0; mt < 4; ++mt)
            #pragma unroll
            for (int nt = 0; nt < 2; ++nt)
                acc[mt][nt] = __builtin_amdgcn_mfma_f32_16x16x32_bf16(
                    aF[mt], bF[nt], acc[mt][nt], 0, 0, 0);
    }

    #pragma unroll
    for (int mt = 0; mt < 4; ++mt) {
        #pragma unroll
        for (int nt = 0; nt < 2; ++nt) {
            int col = (wave << 5) + (nt << 4) + m;
            #pragma unroll
            for (int i = 0; i < 4; ++i) {
                int rr = (mt << 4) + (q << 2) + i;
                if (r0 + rr < N) {
                    float v = acc[mt][nt][i];
                    node_out[(size_t)(r0 + rr) * H + col] = v > 0.f ? v : 0.f;
                }
            }
        }
    }
}

extern "C" void kernel_launch(void* const* d_in, const int* in_sizes, int n_in,
                              void* d_out, int out_size, void* d_ws, size_t ws_size,
                              hipStream_t stream) {
    const float* node_rep = (const float*)d_in[0];
    const float* edge_rep = (const float*)d_in[1];
    const int*   eidx     = (const int*)d_in[2];
    const float* W1       = (const float*)d_in[3];
    const float* W2       = (const float*)d_in[4];
    const float* WL       = (const float*)d_in[5];
    const float* eps1     = (const float*)d_in[6];
    const float* eps2     = (const float*)d_in[7];

    const int N = in_sizes[0] / H;     // 50000
    const int E = in_sizes[1] / H;     // 800000

    float* node_out = (float*)d_out;
    float* edge_out = (float*)d_out + (size_t)N * H;

    // workspace: bf16 weights (128 KB) + fp16 lvl (12.8 MB) + bf16 node_rep (12.8 MB)
    char* ws = (char*)d_ws;
    short* W1T = (short*)ws;                               // 256*128*2 = 64 KB
    short* W2T = (short*)(ws + 65536);                     // 32 KB
    short* WLT = (short*)(ws + 65536 + 32768);             // 32 KB
    unsigned short* lvl = (unsigned short*)(ws + 131072);  // N*H*2 = 12.8 MB
    short* NRB = (short*)(ws + 131072 + (size_t)N * H * 2);

    const int total8 = N * H / 8;      // 800000

    hipMemsetAsync(lvl, 0, (size_t)N * H * sizeof(unsigned short), stream);
    prep_weights<<<128, 256, 0, stream>>>(W1, W2, WL, W1T, W2T, WLT);
    node_prep<<<(total8 + 255) / 256, 256, 0, stream>>>(node_rep, NRB, total8);
    edge_kernel<<<(E + MB - 1) / MB, 256, 0, stream>>>(
        NRB, edge_rep, eidx, W1T, WLT, eps2, lvl, edge_out, E);
    node_kernel<<<(N + MB - 1) / MB, 256, 0, stream>>>(
        NRB, lvl, W2T, eps1, node_out, N);
}